// Round 12
// baseline (158.816 us; speedup 1.0000x reference)
//
#include <hip/hip_runtime.h>

// LinkPredictor: out[e] = W2 . relu(W1s.z[src] + W1d.z[dst] + b1) + b2
// Factored: C = z @ [W1s|W1d]^T  (node GEMM, bf16 MFMA), then per-edge
// gather + fused add/relu/dot.
// GEMM v12 = r10's proven wave body (VGPR 88, 2-deep z prefetch, Wt
// quarter in swizzled LDS, one barrier) at DOUBLE the occupancy:
// 512-thread blocks (8 waves), 64 KB LDS -> 2 blocks/CU = 4 waves/SIMD,
// 1568 non-persistent blocks, XCD-pinned quarter-siblings.

#define NN 100000   // nodes (3125 slots of 32, exact)
#define NE 300000   // edges
#define KD 256      // in channels (K)
#define NO 512      // 2*HID output cols (A | B)

typedef __attribute__((ext_vector_type(8))) short short8;
typedef __attribute__((ext_vector_type(8))) unsigned short ushort8;
typedef __attribute__((ext_vector_type(4))) float f32x4;
typedef __attribute__((ext_vector_type(4))) unsigned int uint4v;

__device__ __forceinline__ unsigned short f2bf(float f) {
  union { float f; unsigned int u; } v; v.f = f;
  unsigned int u = v.u;
  u += 0x7fffu + ((u >> 16) & 1u);   // RNE
  return (unsigned short)(u >> 16);
}
__device__ __forceinline__ float bf2f(unsigned short h) {
  union { unsigned int u; float f; } v; v.u = ((unsigned int)h) << 16;
  return v.f;
}
// pack 2 f32 -> {bf16(a) low, bf16(b) high} (round-half-up)
__device__ __forceinline__ unsigned int pkbf(float a, float b) {
  unsigned int ua = __float_as_uint(a) + 0x8000u;
  unsigned int ub = __float_as_uint(b) + 0x8000u;
  return __builtin_amdgcn_perm(ub, ua, 0x07060302u);
}

// ---- repack W1 (f32 [256][512]) -> Wt (bf16 [512][256], K-contiguous) ----
__global__ void prep_w(const float* __restrict__ W1, unsigned short* __restrict__ Wt) {
  int idx = blockIdx.x * 256 + threadIdx.x;   // 512*256 = 131072
  int j = idx >> 8, k = idx & 255;
  float v = (j < 256) ? W1[j * 512 + k] : W1[(j - 256) * 512 + 256 + k];
  Wt[idx] = f2bf(v);
}

// ---- C[n][j] = sum_k z[n][k] * Wt[j][k]  (natural layout) ----
__global__ __launch_bounds__(512, 4) void gemm_zw(const float* __restrict__ z,
                                                  const unsigned short* __restrict__ Wt,
                                                  unsigned short* __restrict__ C) {
  __shared__ unsigned short Bs[128 * KD];   // 64 KB: Wt quarter, swizzled

  // XCD-pinned: 4 quarter-siblings (q=0..3) share (grpIdx, xcd) -> same
  // z rows on the same XCD's L2.
  const int b = blockIdx.x;            // 0..1567
  const int xcd = b & 7;
  const int rr = b >> 3;               // 0..195
  const int q = rr & 3;                // col quarter
  const int grp = (rr >> 2) * 8 + xcd; // 0..391 (slot group of 8)
  const int n0 = q * 128;

  const int t = threadIdx.x;           // 0..511
  const int w = t >> 6, lane = t & 63;
  const int l15 = lane & 15, l4 = lane >> 4;

  const int slot = grp * 8 + w;        // 32-node slot, 0..3135
  const int node0 = slot * 32;
  const bool live = (slot < 3125);

  // z: band0 row node0+l15, band1 +16; lane k-base l4*8 (clamped if dead)
  const float* zr = z + (size_t)(live ? node0 + l15 : 0) * KD + l4 * 8;

#define LOADZ(kc, Ra, Rb, Rc, Rd)                                  \
  Ra = *(const float4*)(zr + (kc) * 32);                           \
  Rb = *(const float4*)(zr + (kc) * 32 + 4);                       \
  Rc = *(const float4*)(zr + 16 * KD + (kc) * 32);                 \
  Rd = *(const float4*)(zr + 16 * KD + (kc) * 32 + 4);

  float4 Z0a, Z0b, Z0c, Z0d, Z1a, Z1b, Z1c, Z1d;
  // early prefetch: completes for free under the stage-barrier's vmcnt drain
  LOADZ(0, Z0a, Z0b, Z0c, Z0d)
  LOADZ(1, Z1a, Z1b, Z1c, Z1d)
  __builtin_amdgcn_sched_barrier(0);

  // ---- stage Wt quarter: row r (0..127), 16B chunk c stored at c^(r&7)
#pragma unroll
  for (int i = 0; i < 8; ++i) {
    const int id = t + 512 * i;        // 0..4095 chunks
    const int row = id >> 5, c = id & 31;
    ushort8 v = *(const ushort8*)(Wt + (size_t)(n0 + row) * KD + c * 8);
    *(ushort8*)&Bs[row * KD + ((c ^ (row & 7)) << 3)] = v;
  }
  __syncthreads();                     // the ONLY barrier

  if (!live) return;                   // tail waves (11 of 3136) exit

  f32x4 acc0[8], acc1[8];
#pragma unroll
  for (int f = 0; f < 8; ++f) { acc0[f] = (f32x4)0.f; acc1[f] = (f32x4)0.f; }

  // per k-step: pack (consume buf) -> refill buf (kc+2) -> 8 wt-frags x 2 MFMA
#define KSTEP(kc, Ra, Rb, Rc, Rd, PF)                                   \
  {                                                                     \
    union { uint4v u; short8 s; } zb0, zb1;                             \
    zb0.u[0] = pkbf(Ra.x, Ra.y); zb0.u[1] = pkbf(Ra.z, Ra.w);           \
    zb0.u[2] = pkbf(Rb.x, Rb.y); zb0.u[3] = pkbf(Rb.z, Rb.w);           \
    zb1.u[0] = pkbf(Rc.x, Rc.y); zb1.u[1] = pkbf(Rc.z, Rc.w);           \
    zb1.u[2] = pkbf(Rd.x, Rd.y); zb1.u[3] = pkbf(Rd.z, Rd.w);           \
    if (PF) { LOADZ((kc) + 2, Ra, Rb, Rc, Rd)                           \
              __builtin_amdgcn_sched_barrier(0); }                      \
    _Pragma("unroll")                                                   \
    for (int f = 0; f < 8; ++f) {                                       \
      union { ushort8 u; short8 s; } wv;                                \
      wv.u = *(const ushort8*)&Bs[(f * 16 + l15) * KD +                 \
                                  ((((kc) * 4 + l4) ^ (l15 & 7)) << 3)];\
      acc0[f] = __builtin_amdgcn_mfma_f32_16x16x32_bf16(wv.s, zb0.s, acc0[f], 0, 0, 0); \
      acc1[f] = __builtin_amdgcn_mfma_f32_16x16x32_bf16(wv.s, zb1.s, acc1[f], 0, 0, 0); \
    }                                                                   \
  }

  KSTEP(0, Z0a, Z0b, Z0c, Z0d, 1)
  KSTEP(1, Z1a, Z1b, Z1c, Z1d, 1)
  KSTEP(2, Z0a, Z0b, Z0c, Z0d, 1)
  KSTEP(3, Z1a, Z1b, Z1c, Z1d, 1)
  KSTEP(4, Z0a, Z0b, Z0c, Z0d, 1)
  KSTEP(5, Z1a, Z1b, Z1c, Z1d, 1)
  KSTEP(6, Z0a, Z0b, Z0c, Z0d, 0)
  KSTEP(7, Z1a, Z1b, Z1c, Z1d, 0)
#undef KSTEP
#undef LOADZ

  // store: lane holds node (l15/band) x wt-cols {n0+f*16+l4*4+0..3}
#pragma unroll
  for (int f = 0; f < 8; ++f) {
    uint2 p;
    p.x = pkbf(acc0[f][0], acc0[f][1]);
    p.y = pkbf(acc0[f][2], acc0[f][3]);
    *(uint2*)(C + (size_t)(node0 + l15) * NO + n0 + f * 16 + l4 * 4) = p;
    p.x = pkbf(acc1[f][0], acc1[f][1]);
    p.y = pkbf(acc1[f][2], acc1[f][3]);
    *(uint2*)(C + (size_t)(node0 + 16 + l15) * NO + n0 + f * 16 + l4 * 4) = p;
  }
}

// ---- per-edge: out[e] = b2 + sum W2[h]*relu(A[s][h] + B[d][h] + b1[h]) ----
__global__ __launch_bounds__(256) void edge_mlp(const unsigned short* __restrict__ C,
                                                const int* __restrict__ ei,
                                                const float* __restrict__ b1,
                                                const float* __restrict__ W2,
                                                const float* __restrict__ b2,
                                                float* __restrict__ out) {
  const int t = threadIdx.x;
  const int lane = t & 63;
  const int g = lane >> 4;           // edge slot within wave (0..3)
  const int c0 = (lane & 15) * 16;   // channel base for this lane
  float b1v[16], w2v[16];
#pragma unroll
  for (int i = 0; i < 16; ++i) { b1v[i] = b1[c0 + i]; w2v[i] = W2[c0 + i]; }
  const float bias2 = b2[0];
  const int waveId = blockIdx.x * 4 + (t >> 6);
  const int nw = gridDim.x * 4;
  for (int e0 = waveId * 4; e0 < NE; e0 += nw * 4) {
    const int e = e0 + g;                 // NE % 4 == 0 -> always valid
    const int sn = ei[e];
    const int dn = ei[NE + e];
    const ushort8* ap = (const ushort8*)(C + (size_t)sn * NO + c0);
    const ushort8* bp = (const ushort8*)(C + (size_t)dn * NO + 256 + c0);
    ushort8 a0 = ap[0], a1 = ap[1];
    ushort8 v0 = bp[0], v1 = bp[1];
    float partial = 0.f;
#pragma unroll
    for (int j = 0; j < 8; ++j) {
      float h = bf2f(a0[j]) + bf2f(v0[j]) + b1v[j];
      h = fmaxf(h, 0.f);
      partial = fmaf(h, w2v[j], partial);
    }
#pragma unroll
    for (int j = 0; j < 8; ++j) {
      float h = bf2f(a1[j]) + bf2f(v1[j]) + b1v[8 + j];
      h = fmaxf(h, 0.f);
      partial = fmaf(h, w2v[8 + j], partial);
    }
    partial += __shfl_xor(partial, 8);
    partial += __shfl_xor(partial, 4);
    partial += __shfl_xor(partial, 2);
    partial += __shfl_xor(partial, 1);
    if ((lane & 15) == 0) out[e] = partial + bias2;
  }
}

extern "C" void kernel_launch(void* const* d_in, const int* in_sizes, int n_in,
                              void* d_out, int out_size, void* d_ws, size_t ws_size,
                              hipStream_t stream) {
  const float* z  = (const float*)d_in[0];
  const float* W1 = (const float*)d_in[1];
  const float* b1 = (const float*)d_in[2];
  const float* W2 = (const float*)d_in[3];
  const float* b2 = (const float*)d_in[4];
  const int*   ei = (const int*)d_in[5];
  float* out = (float*)d_out;

  unsigned short* C  = (unsigned short*)d_ws;          // 100000*512 bf16 = 102.4 MB
  unsigned short* Wt = C + (size_t)NN * NO;            // 512*256 bf16 = 256 KB

  prep_w<<<512, 256, 0, stream>>>(W1, Wt);
  gemm_zw<<<1568, 512, 0, stream>>>(z, Wt, C);
  edge_mlp<<<2048, 256, 0, stream>>>(C, ei, b1, W2, b2, out);
}

// Round 13
// 127.229 us; speedup vs baseline: 1.2483x; 1.2483x over previous
//
#include <hip/hip_runtime.h>

// LinkPredictor: out[e] = W2 . relu(W1s.z[src] + W1d.z[dst] + b1) + b2
// Factored: C = z @ [W1s|W1d]^T  (node GEMM, bf16 MFMA), then per-edge
// gather + fused add/relu/dot.
// GEMM v13 = r6's gll+LDS pipeline (loads in flight cost no VGPRs,
// counted per-wave vmcnt, zero K-loop barriers) at 2 waves/SIMD:
// 512-thread blocks, per-wave A dbuf 2x4KB (32-col chunks), Wt quarter
// in 64 KB swizzled LDS staged once, XCD-pinned quarter-siblings.

#define NN 100000   // nodes (3125 slots of 32, exact)
#define NE 300000   // edges
#define KD 256      // in channels (K)
#define NO 512      // 2*HID output cols (A | B)

typedef __attribute__((ext_vector_type(8))) short short8;
typedef __attribute__((ext_vector_type(8))) unsigned short ushort8;
typedef __attribute__((ext_vector_type(4))) float f32x4;
typedef __attribute__((ext_vector_type(4))) unsigned int uint4v;

__device__ __forceinline__ unsigned short f2bf(float f) {
  union { float f; unsigned int u; } v; v.f = f;
  unsigned int u = v.u;
  u += 0x7fffu + ((u >> 16) & 1u);   // RNE
  return (unsigned short)(u >> 16);
}
__device__ __forceinline__ float bf2f(unsigned short h) {
  union { unsigned int u; float f; } v; v.u = ((unsigned int)h) << 16;
  return v.f;
}
// pack 2 f32 -> {bf16(a) low, bf16(b) high} (round-half-up)
__device__ __forceinline__ unsigned int pkbf(float a, float b) {
  unsigned int ua = __float_as_uint(a) + 0x8000u;
  unsigned int ub = __float_as_uint(b) + 0x8000u;
  return __builtin_amdgcn_perm(ub, ua, 0x07060302u);
}

// ---- repack W1 (f32 [256][512]) -> Wt (bf16 [512][256], K-contiguous) ----
__global__ void prep_w(const float* __restrict__ W1, unsigned short* __restrict__ Wt) {
  int idx = blockIdx.x * 256 + threadIdx.x;   // 512*256 = 131072
  int j = idx >> 8, k = idx & 255;
  float v = (j < 256) ? W1[j * 512 + k] : W1[(j - 256) * 512 + 256 + k];
  Wt[idx] = f2bf(v);
}

// ---- C[n][j] = sum_k z[n][k] * Wt[j][k]  (natural layout) ----
__global__ __launch_bounds__(512, 2) void gemm_zw(const float* __restrict__ z,
                                                  const unsigned short* __restrict__ Wt,
                                                  unsigned short* __restrict__ C) {
  __shared__ unsigned short Bs[128 * KD];   // 64 KB: Wt quarter, swizzled
  __shared__ float Aw[8][2][1024];          // 8 waves x dbuf x 4 KB = 64 KB

  // XCD-pinned: 4 quarter-siblings share (grp, xcd) -> same z rows, same L2
  const int b = blockIdx.x;            // 0..1567
  const int xcd = b & 7;
  const int rr = b >> 3;               // 0..195
  const int q = rr & 3;                // col quarter
  const int grp = (rr >> 2) * 8 + xcd; // 0..391
  const int n0 = q * 128;

  const int t = threadIdx.x;           // 0..511
  const int w = t >> 6, lane = t & 63;
  const int l15 = lane & 15, l4 = lane >> 4;

  const int slot = grp * 8 + w;        // 32-node slot, 0..3135
  const bool live = (slot < 3125);
  const int node0 = live ? slot * 32 : 0;   // clamp dead waves (harmless)

  // gll sources: issue j covers rows j*8+(lane>>3); 16B chunk pre-swizzled
  // so LDS stays gll-linear (base + lane*16) but ds_read is ~2-way max.
  const float* gp[4];
#pragma unroll
  for (int j = 0; j < 4; ++j)
    gp[j] = z + (size_t)(node0 + j * 8 + (lane >> 3)) * KD +
            (((lane & 7) ^ (lane >> 3)) << 2);
  float* Ab0 = &Aw[w][0][0];
  float* Ab1 = &Aw[w][1][0];

#define ISSUE(kc, dst)                                                         \
  { _Pragma("unroll")                                                          \
    for (int j = 0; j < 4; ++j)                                                \
      __builtin_amdgcn_global_load_lds(                                        \
        (const __attribute__((address_space(1))) unsigned int*)(gp[j] + (kc) * 32), \
        (__attribute__((address_space(3))) unsigned int*)((dst) + j * 256),    \
        16, 0, 0); }                                                           \
  __builtin_amdgcn_sched_barrier(0);

  // prologue: chunks 0,1 in flight before the stage barrier (drain absorbs)
  ISSUE(0, Ab0)
  ISSUE(1, Ab1)

  // ---- stage Wt quarter: row r (0..127), 16B chunk c stored at c^(r&7)
#pragma unroll
  for (int i = 0; i < 8; ++i) {
    const int id = t + 512 * i;        // 0..4095 chunks
    const int row = id >> 5, c = id & 31;
    ushort8 v = *(const ushort8*)(Wt + (size_t)(n0 + row) * KD + c * 8);
    *(ushort8*)&Bs[row * KD + ((c ^ (row & 7)) << 3)] = v;
  }
  __syncthreads();                     // the ONLY barrier

  if (!live) return;                   // dead tail waves exit after barrier

  f32x4 acc0[8], acc1[8];
#pragma unroll
  for (int f = 0; f < 8; ++f) { acc0[f] = (f32x4)0.f; acc1[f] = (f32x4)0.f; }

  // chunk kc (32 cols): wait arrived -> 4x float4 ds_read -> drain -> issue
  // kc+2 into the freed buffer -> pack -> 8 wt-frags x 2 bands MFMA
#define CHUNK(kc, Ab, WAITN, PF)                                               \
  {                                                                            \
    asm volatile("s_waitcnt vmcnt(" #WAITN ")" ::: "memory");                  \
    __builtin_amdgcn_sched_barrier(0);                                         \
    const int co0 = ((l4 << 1) ^ (l15 & 7)) << 2;                              \
    const int co1 = (((l4 << 1) | 1) ^ (l15 & 7)) << 2;                        \
    float4 av0 = *(const float4*)&(Ab)[l15 * 32 + co0];                        \
    float4 av1 = *(const float4*)&(Ab)[l15 * 32 + co1];                        \
    float4 av2 = *(const float4*)&(Ab)[(16 + l15) * 32 + co0];                 \
    float4 av3 = *(const float4*)&(Ab)[(16 + l15) * 32 + co1];                 \
    asm volatile("s_waitcnt lgkmcnt(0)" ::: "memory");                         \
    __builtin_amdgcn_sched_barrier(0);                                         \
    if (PF) ISSUE((kc) + 2, Ab)                                                \
    union { uint4v u; short8 s; } zb0, zb1;                                    \
    zb0.u[0] = pkbf(av0.x, av0.y); zb0.u[1] = pkbf(av0.z, av0.w);              \
    zb0.u[2] = pkbf(av1.x, av1.y); zb0.u[3] = pkbf(av1.z, av1.w);              \
    zb1.u[0] = pkbf(av2.x, av2.y); zb1.u[1] = pkbf(av2.z, av2.w);              \
    zb1.u[2] = pkbf(av3.x, av3.y); zb1.u[3] = pkbf(av3.z, av3.w);              \
    _Pragma("unroll")                                                          \
    for (int f = 0; f < 8; ++f) {                                              \
      union { ushort8 u; short8 s; } wv;                                       \
      wv.u = *(const ushort8*)&Bs[(f * 16 + l15) * KD +                        \
                                  ((((kc) * 4 + l4) ^ (l15 & 7)) << 3)];       \
      acc0[f] = __builtin_amdgcn_mfma_f32_16x16x32_bf16(wv.s, zb0.s, acc0[f], 0, 0, 0); \
      acc1[f] = __builtin_amdgcn_mfma_f32_16x16x32_bf16(wv.s, zb1.s, acc1[f], 0, 0, 0); \
    }                                                                          \
  }

  CHUNK(0, Ab0, 4, 1)
  CHUNK(1, Ab1, 4, 1)
  CHUNK(2, Ab0, 4, 1)
  CHUNK(3, Ab1, 4, 1)
  CHUNK(4, Ab0, 4, 1)
  CHUNK(5, Ab1, 4, 1)
  CHUNK(6, Ab0, 4, 0)
  CHUNK(7, Ab1, 0, 0)
#undef CHUNK
#undef ISSUE

  // store: lane holds node (l15/band) x wt-cols {n0+f*16+l4*4+0..3}
#pragma unroll
  for (int f = 0; f < 8; ++f) {
    uint2 p;
    p.x = pkbf(acc0[f][0], acc0[f][1]);
    p.y = pkbf(acc0[f][2], acc0[f][3]);
    *(uint2*)(C + (size_t)(node0 + l15) * NO + n0 + f * 16 + l4 * 4) = p;
    p.x = pkbf(acc1[f][0], acc1[f][1]);
    p.y = pkbf(acc1[f][2], acc1[f][3]);
    *(uint2*)(C + (size_t)(node0 + 16 + l15) * NO + n0 + f * 16 + l4 * 4) = p;
  }
}

// ---- per-edge: out[e] = b2 + sum W2[h]*relu(A[s][h] + B[d][h] + b1[h]) ----
__global__ __launch_bounds__(256) void edge_mlp(const unsigned short* __restrict__ C,
                                                const int* __restrict__ ei,
                                                const float* __restrict__ b1,
                                                const float* __restrict__ W2,
                                                const float* __restrict__ b2,
                                                float* __restrict__ out) {
  const int t = threadIdx.x;
  const int lane = t & 63;
  const int g = lane >> 4;           // edge slot within wave (0..3)
  const int c0 = (lane & 15) * 16;   // channel base for this lane
  float b1v[16], w2v[16];
#pragma unroll
  for (int i = 0; i < 16; ++i) { b1v[i] = b1[c0 + i]; w2v[i] = W2[c0 + i]; }
  const float bias2 = b2[0];
  const int waveId = blockIdx.x * 4 + (t >> 6);
  const int nw = gridDim.x * 4;
  for (int e0 = waveId * 4; e0 < NE; e0 += nw * 4) {
    const int e = e0 + g;                 // NE % 4 == 0 -> always valid
    const int sn = ei[e];
    const int dn = ei[NE + e];
    const ushort8* ap = (const ushort8*)(C + (size_t)sn * NO + c0);
    const ushort8* bp = (const ushort8*)(C + (size_t)dn * NO + 256 + c0);
    ushort8 a0 = ap[0], a1 = ap[1];
    ushort8 v0 = bp[0], v1 = bp[1];
    float partial = 0.f;
#pragma unroll
    for (int j = 0; j < 8; ++j) {
      float h = bf2f(a0[j]) + bf2f(v0[j]) + b1v[j];
      h = fmaxf(h, 0.f);
      partial = fmaf(h, w2v[j], partial);
    }
#pragma unroll
    for (int j = 0; j < 8; ++j) {
      float h = bf2f(a1[j]) + bf2f(v1[j]) + b1v[8 + j];
      h = fmaxf(h, 0.f);
      partial = fmaf(h, w2v[8 + j], partial);
    }
    partial += __shfl_xor(partial, 8);
    partial += __shfl_xor(partial, 4);
    partial += __shfl_xor(partial, 2);
    partial += __shfl_xor(partial, 1);
    if ((lane & 15) == 0) out[e] = partial + bias2;
  }
}

extern "C" void kernel_launch(void* const* d_in, const int* in_sizes, int n_in,
                              void* d_out, int out_size, void* d_ws, size_t ws_size,
                              hipStream_t stream) {
  const float* z  = (const float*)d_in[0];
  const float* W1 = (const float*)d_in[1];
  const float* b1 = (const float*)d_in[2];
  const float* W2 = (const float*)d_in[3];
  const float* b2 = (const float*)d_in[4];
  const int*   ei = (const int*)d_in[5];
  float* out = (float*)d_out;

  unsigned short* C  = (unsigned short*)d_ws;          // 100000*512 bf16 = 102.4 MB
  unsigned short* Wt = C + (size_t)NN * NO;            // 512*256 bf16 = 256 KB

  prep_w<<<512, 256, 0, stream>>>(W1, Wt);
  gemm_zw<<<1568, 512, 0, stream>>>(z, Wt, C);
  edge_mlp<<<2048, 256, 0, stream>>>(C, ei, b1, W2, b2, out);
}